// Round 5
// baseline (1228.853 us; speedup 1.0000x reference)
//
#include <hip/hip_runtime.h>

// Child-Sum Tree-LSTM, level-synchronous, B=8 L=8192 D=768.
// Per level: 5 fused K=768 GEMM products + LSTM cell epilogue.
//   acc0..2 (i,o,u) = hs @ (0.5*W_iou + U_iou)^T
//   acc3 (fl-pre)   = hl@Wfp^T + hr@Wfh^T,  Wfp = 0.5*W_f + U_f, Wfh = 0.5*W_f
//   acc4 (fr-pre)   = hl@Wfh^T + hr@Wfp^T
// fp16 MFMA 16x16x32, fp32 accum. Block = 128 rows x 64 cols, 256 thr
// (4 waves 2x2, wave tile 64x32). Double-buffered 36.9KB LDS -> 2 blocks/CU.
// K-loop: vmcnt(0)+B1 (prior-kt DMA landed) -> ds_reads -> STAGE(next) issued
// mid-kt (hides under MFMA) -> MFMA cluster -> B2. No setprio (it serializes
// the 2-block anti-phase overlap). mb-major block order for H L2/L3 reuse.

typedef _Float16 half8 __attribute__((ext_vector_type(8)));
typedef float f32x4 __attribute__((ext_vector_type(4)));

#define ROWB 1536        // bytes per 768-elem fp16 row
#define NT 24            // 768 / 32
#define BUFB 36864       // A 16384 + B 20480
#define MATB 1179648     // 768*768*2 bytes per weight mat

__device__ __forceinline__ float sigm(float x){ return 1.f/(1.f+__expf(-x)); }
__device__ __forceinline__ float tanhfast(float x){ return 1.f - 2.f/(1.f+__expf(2.f*x)); }

__device__ __forceinline__ void gload16(const void* g, void* l){
  __builtin_amdgcn_global_load_lds((const __attribute__((address_space(1))) void*)g,
                                   (__attribute__((address_space(3))) void*)l, 16, 0, 0);
}

// Bw: 5 mats of 768x768 fp16: [0..2]=0.5*W_iou+U_iou (i,o,u), [3]=0.5*Wf+Uf, [4]=0.5*Wf
__global__ void prep_weights(const float* __restrict__ Wiou, const float* __restrict__ Uiou,
                             const float* __restrict__ Wf, const float* __restrict__ Uf,
                             _Float16* __restrict__ Bw)
{
    const int n1 = 2304 * 768, n2 = n1 + 589824, n3 = n2 + 589824;
    int stride = gridDim.x * blockDim.x;
    for (int idx = blockIdx.x * blockDim.x + threadIdx.x; idx < n3; idx += stride) {
        float v;
        if (idx < n1)      v = __fmaf_rn(0.5f, Wiou[idx], Uiou[idx]);
        else if (idx < n2) { int k = idx - n1; v = __fmaf_rn(0.5f, Wf[k], Uf[k]); }
        else               { int k = idx - n2; v = 0.5f * Wf[k]; }
        Bw[idx] = (_Float16)v;
    }
}

__global__ void cast_leaves(const float* __restrict__ x, _Float16* __restrict__ h, int n8)
{
    int stride = gridDim.x * blockDim.x;
    for (int i = blockIdx.x * blockDim.x + threadIdx.x; i < n8; i += stride) {
        float4 v0 = ((const float4*)x)[2 * i];
        float4 v1 = ((const float4*)x)[2 * i + 1];
        half8 o = { (_Float16)v0.x, (_Float16)v0.y, (_Float16)v0.z, (_Float16)v0.w,
                    (_Float16)v1.x, (_Float16)v1.y, (_Float16)v1.z, (_Float16)v1.w };
        ((half8*)h)[i] = o;
    }
}

// LDS per buffer:
//  A: 128 rows x 128B. Row r chunk j: jj=j^(r&7); side=jj>>2 (0=HL,1=HR),
//     kchunk=jj&3 of H row 2*(mBase+r)+side.
//  B at +16384: 5 mats x 32 pairs x 128B (mat stride 4096). Pair p chunk j:
//     jj=j^(p&7); col=d0+2p+(jj>>2), kchunk=jj&3.
__global__ __launch_bounds__(256, 2) void tree_level(
    const _Float16* __restrict__ Hc, const float* __restrict__ Cc,
    const _Float16* __restrict__ Bw,
    const float* __restrict__ biou, const float* __restrict__ bfv,
    _Float16* __restrict__ Hn, float* __restrict__ Cn,
    float* __restrict__ outH, float* __restrict__ outC,
    int M, int mblocks, int firstLevel, int finalLevel)
{
    __shared__ __align__(16) char smem[2 * BUFB];
    const int tid = threadIdx.x;
    const int lane = tid & 63;
    const int w = tid >> 6;        // 0..3
    const int wm = w >> 1;         // 0..1 row-wave (64 rows each)
    const int wd = w & 1;          // 0..1 col-wave (32 cols each)

    // bijective XCD chunking; mb-major within XCD (12 same-mb blocks adjacent
    // -> H tile served from L2/L3, weights L3-resident)
    const int nwg = mblocks * 12;
    const int orig = blockIdx.x;
    const int xcd = orig & 7, qx = nwg >> 3, rx = nwg & 7;
    const int v = (xcd < rx ? xcd * (qx + 1) : rx * (qx + 1) + (xcd - rx) * qx) + (orig >> 3);
    const int mb = v / 12;
    const int d0c = v - mb * 12;
    const int mBase = mb * 128;
    const int d0 = d0c * 64;

    // ---- stage-source precompute (compile-time A/B slot split: s<4 = A) ----
    const int l3 = lane >> 3, j = lane & 7;
    const int rbase = w * 8 + l3;          // 0..31
    const int jjA = j ^ l3;                // (rA&7) == l3 for all s
    unsigned offH[4];
#pragma unroll
    for (int s = 0; s < 4; ++s) {
        int gr = mBase + s * 32 + rbase;
        if (gr >= M) gr = M - 1;
        offH[s] = (unsigned)(2 * gr + (jjA >> 2)) * ROWB + (jjA & 3) * 16;
    }
    const int pB = w * 8 + l3;             // 0..31
    const int jjB = j ^ (pB & 7);
    const unsigned offWcol = (unsigned)(d0 + 2 * pB + (jjB >> 2)) * ROWB + (jjB & 3) * 16;
    const int wK = w * 1024;               // uniform part of LDS dest

#define STAGE(bi, ko) do { \
    _Pragma("unroll") for (int s = 0; s < 4; ++s) \
        gload16((const char*)Hc + offH[s] + (ko), smem + (bi) * BUFB + s * 4096 + wK); \
    _Pragma("unroll") for (int s = 0; s < 5; ++s) \
        gload16((const char*)Bw + (size_t)s * MATB + offWcol + (ko), \
                smem + (bi) * BUFB + 16384 + s * 4096 + wK); \
} while (0)

    // ---- compute offsets (kt-invariant) ----
    const int q = lane >> 4;       // K-slice / C-row-group
    const int lr = lane & 15;
    int offA[4], offB[2];
#pragma unroll
    for (int fm = 0; fm < 4; ++fm) {
        int r = wm * 64 + fm * 16 + lr;
        offA[fm] = r * 128 + ((q ^ (r & 7)) * 16);
    }
#pragma unroll
    for (int fd = 0; fd < 2; ++fd) {
        int cl = wd * 32 + fd * 16 + lr;
        int p = cl >> 1;
        int jb = ((cl & 1) * 4 + q) ^ (p & 7);
        offB[fd] = 16384 + p * 128 + jb * 16;
    }

    f32x4 acc[5][4][2];
#pragma unroll
    for (int g = 0; g < 5; ++g)
#pragma unroll
        for (int a = 0; a < 4; ++a)
#pragma unroll
            for (int b = 0; b < 2; ++b)
                acc[g][a][b] = (f32x4){0.f, 0.f, 0.f, 0.f};

    // ---- main loop ----
    STAGE(0, 0);
    int cur = 0;
    for (int kt = 0; kt < NT; ++kt) {
        asm volatile("s_waitcnt vmcnt(0)" ::: "memory");  // buf[cur] DMA landed (issued ~3/4 kt ago)
        __builtin_amdgcn_s_barrier();                     // ... for ALL waves
        const char* bb = smem + cur * BUFB;
        half8 hl[4], hr[4], hs[4];
        half8 bfrag[2][5];
#pragma unroll
        for (int fm = 0; fm < 4; ++fm) {
            hl[fm] = *(const half8*)(bb + offA[fm]);
            hr[fm] = *(const half8*)(bb + (offA[fm] ^ 64));
        }
#pragma unroll
        for (int fd = 0; fd < 2; ++fd) {
            const char* bp = bb + offB[fd];
#pragma unroll
            for (int t = 0; t < 5; ++t)
                bfrag[fd][t] = *(const half8*)(bp + t * 4096);
        }
        if (kt + 1 < NT) STAGE(cur ^ 1, (kt + 1) * 64);   // issue mid-kt; hides under MFMA
        __builtin_amdgcn_sched_barrier(0);                // keep stage-issue above MFMA burst
#pragma unroll
        for (int fm = 0; fm < 4; ++fm) hs[fm] = hl[fm] + hr[fm];
#pragma unroll
        for (int fd = 0; fd < 2; ++fd) {
#pragma unroll
            for (int fm = 0; fm < 4; ++fm) {
                acc[0][fm][fd] = __builtin_amdgcn_mfma_f32_16x16x32_f16(hs[fm], bfrag[fd][0], acc[0][fm][fd], 0, 0, 0);
                acc[1][fm][fd] = __builtin_amdgcn_mfma_f32_16x16x32_f16(hs[fm], bfrag[fd][1], acc[1][fm][fd], 0, 0, 0);
                acc[2][fm][fd] = __builtin_amdgcn_mfma_f32_16x16x32_f16(hs[fm], bfrag[fd][2], acc[2][fm][fd], 0, 0, 0);
                acc[3][fm][fd] = __builtin_amdgcn_mfma_f32_16x16x32_f16(hl[fm], bfrag[fd][3], acc[3][fm][fd], 0, 0, 0);
                acc[3][fm][fd] = __builtin_amdgcn_mfma_f32_16x16x32_f16(hr[fm], bfrag[fd][4], acc[3][fm][fd], 0, 0, 0);
                acc[4][fm][fd] = __builtin_amdgcn_mfma_f32_16x16x32_f16(hl[fm], bfrag[fd][4], acc[4][fm][fd], 0, 0, 0);
                acc[4][fm][fd] = __builtin_amdgcn_mfma_f32_16x16x32_f16(hr[fm], bfrag[fd][3], acc[4][fm][fd], 0, 0, 0);
            }
        }
        if (kt + 1 < NT) __builtin_amdgcn_s_barrier();    // all waves done reading buf[cur]
        cur ^= 1;
    }

    // ---- LSTM cell epilogue, in-register ----
#pragma unroll
    for (int fd = 0; fd < 2; ++fd) {
        const int col = d0 + wd * 32 + fd * 16 + lr;
        const float bi = biou[col];
        const float bo = biou[768 + col];
        const float bu = biou[1536 + col];
        const float bf = bfv[col];
#pragma unroll
        for (int fm = 0; fm < 4; ++fm) {
            const int rb = mBase + wm * 64 + fm * 16 + q * 4;
#pragma unroll
            for (int r4 = 0; r4 < 4; ++r4) {
                int row = rb + r4;
                if (row < M) {
                    float iv = acc[0][fm][fd][r4] + bi;
                    float ov = acc[1][fm][fd][r4] + bo;
                    float uv = acc[2][fm][fd][r4] + bu;
                    float fl = sigm(acc[3][fm][fd][r4] + bf);
                    float fr = sigm(acc[4][fm][fd][r4] + bf);
                    float clv = 0.f, crv = 0.f;
                    if (!firstLevel) {
                        clv = Cc[(size_t)(2 * row) * 768 + col];
                        crv = Cc[(size_t)(2 * row + 1) * 768 + col];
                    }
                    float c = sigm(iv) * tanhfast(uv) + fl * clv + fr * crv;
                    float h = sigm(ov) * tanhfast(c);
                    if (finalLevel) {
                        outH[row * 768 + col] = h;
                        outC[row * 768 + col] = c;
                    } else {
                        Hn[(size_t)row * 768 + col] = (_Float16)h;
                        Cn[(size_t)row * 768 + col] = c;
                    }
                }
            }
        }
    }
}

extern "C" void kernel_launch(void* const* d_in, const int* in_sizes, int n_in,
                              void* d_out, int out_size, void* d_ws, size_t ws_size,
                              hipStream_t stream)
{
    const float* leaf = (const float*)d_in[0];
    const float* Wiou = (const float*)d_in[1];
    const float* biou = (const float*)d_in[2];
    const float* Uiou = (const float*)d_in[3];
    const float* Wf   = (const float*)d_in[4];
    const float* bfv  = (const float*)d_in[5];
    const float* Uf   = (const float*)d_in[6];

    char* ws = (char*)d_ws;
    _Float16* Bw = (_Float16*)(ws);                  // 5x768x768 fp16 = 5,898,240 B
    _Float16* H0 = (_Float16*)(ws + 5898240);        // 65536x768 fp16
    _Float16* H1 = (_Float16*)(ws + 106561536);      // 32768x768 fp16
    float*    C0 = (float*)(ws + 156893184);         // 32768x768 f32
    float*    C1 = (float*)(ws + 257556480);         // 16384x768 f32

    prep_weights<<<1024, 256, 0, stream>>>(Wiou, Uiou, Wf, Uf, Bw);
    cast_leaves<<<2048, 256, 0, stream>>>(leaf, H0, 50331648 / 8);

    float* out = (float*)d_out;  // [2,8,768]
    _Float16* Hc = H0; _Float16* Hn = H1;
    float* Cc = C1; float* Cn = C0;
    int rows = 65536, level = 0;
    while (rows > 8) {
        int M = rows >> 1;
        int fin = (M == 8) ? 1 : 0;
        int mblocks = (M + 127) / 128;
        tree_level<<<mblocks * 12, 256, 0, stream>>>(Hc, Cc, Bw, biou, bfv,
            Hn, Cn, fin ? out : (float*)nullptr, fin ? out + 6144 : (float*)nullptr,
            M, mblocks, level == 0 ? 1 : 0, fin);
        _Float16* th = Hc; Hc = Hn; Hn = th;
        float* tc = Cc; Cc = Cn; Cn = tc;
        rows = M; ++level;
    }
}

// Round 6
// 1038.753 us; speedup vs baseline: 1.1830x; 1.1830x over previous
//
#include <hip/hip_runtime.h>

// Child-Sum Tree-LSTM, level-synchronous, B=8 L=8192 D=768.
// Per level: 5 fused K=768 GEMM products + LSTM cell epilogue.
//   acc0..2 (i,o,u) = hs @ (0.5*W_iou + U_iou)^T
//   acc3 (fl-pre)   = hl@Wfp^T + hr@Wfh^T,  Wfp = 0.5*W_f + U_f, Wfh = 0.5*W_f
//   acc4 (fr-pre)   = hl@Wfh^T + hr@Wfp^T
// fp16 MFMA 16x16x32, fp32 accum. Block = 128 rows x 64 cols, 256 thr
// (4 waves 2x2, wave tile 64x32). Double-buffered 36.9KB LDS -> 2 blocks/CU.
// K-loop (R4 skeleton + T3 phase split):
//   STAGE(kt+1) at top, counted vmcnt(9) -> full-kt DMA landing window
//   B1; phase A {ds_read A + B(fd0), 28 MFMA}; mid s_barrier;
//   phase B {ds_read B(fd1), 28 MFMA}; B2.  setprio(1) around MFMA clusters.
// mb-major block order within XCD (H tile L2/L3-served: FETCH -55%, r5).

typedef _Float16 half8 __attribute__((ext_vector_type(8)));
typedef float f32x4 __attribute__((ext_vector_type(4)));

#define ROWB 1536        // bytes per 768-elem fp16 row
#define NT 24            // 768 / 32
#define BUFB 36864       // A 16384 + B 20480
#define MATB 1179648     // 768*768*2 bytes per weight mat

__device__ __forceinline__ float sigm(float x){ return 1.f/(1.f+__expf(-x)); }
__device__ __forceinline__ float tanhfast(float x){ return 1.f - 2.f/(1.f+__expf(2.f*x)); }

__device__ __forceinline__ void gload16(const void* g, void* l){
  __builtin_amdgcn_global_load_lds((const __attribute__((address_space(1))) void*)g,
                                   (__attribute__((address_space(3))) void*)l, 16, 0, 0);
}

// Bw: 5 mats of 768x768 fp16: [0..2]=0.5*W_iou+U_iou (i,o,u), [3]=0.5*Wf+Uf, [4]=0.5*Wf
__global__ void prep_weights(const float* __restrict__ Wiou, const float* __restrict__ Uiou,
                             const float* __restrict__ Wf, const float* __restrict__ Uf,
                             _Float16* __restrict__ Bw)
{
    const int n1 = 2304 * 768, n2 = n1 + 589824, n3 = n2 + 589824;
    int stride = gridDim.x * blockDim.x;
    for (int idx = blockIdx.x * blockDim.x + threadIdx.x; idx < n3; idx += stride) {
        float v;
        if (idx < n1)      v = __fmaf_rn(0.5f, Wiou[idx], Uiou[idx]);
        else if (idx < n2) { int k = idx - n1; v = __fmaf_rn(0.5f, Wf[k], Uf[k]); }
        else               { int k = idx - n2; v = 0.5f * Wf[k]; }
        Bw[idx] = (_Float16)v;
    }
}

__global__ void cast_leaves(const float* __restrict__ x, _Float16* __restrict__ h, int n8)
{
    int stride = gridDim.x * blockDim.x;
    for (int i = blockIdx.x * blockDim.x + threadIdx.x; i < n8; i += stride) {
        float4 v0 = ((const float4*)x)[2 * i];
        float4 v1 = ((const float4*)x)[2 * i + 1];
        half8 o = { (_Float16)v0.x, (_Float16)v0.y, (_Float16)v0.z, (_Float16)v0.w,
                    (_Float16)v1.x, (_Float16)v1.y, (_Float16)v1.z, (_Float16)v1.w };
        ((half8*)h)[i] = o;
    }
}

// LDS per buffer:
//  A: 128 rows x 128B. Row r chunk j: jj=j^(r&7); side=jj>>2 (0=HL,1=HR),
//     kchunk=jj&3 of H row 2*(mBase+r)+side.
//  B at +16384: 5 mats x 32 pairs x 128B (mat stride 4096). Pair p chunk j:
//     jj=j^(p&7); col=d0+2p+(jj>>2), kchunk=jj&3.
__global__ __launch_bounds__(256, 2) void tree_level(
    const _Float16* __restrict__ Hc, const float* __restrict__ Cc,
    const _Float16* __restrict__ Bw,
    const float* __restrict__ biou, const float* __restrict__ bfv,
    _Float16* __restrict__ Hn, float* __restrict__ Cn,
    float* __restrict__ outH, float* __restrict__ outC,
    int M, int mblocks, int firstLevel, int finalLevel)
{
    __shared__ __align__(16) char smem[2 * BUFB];
    const int tid = threadIdx.x;
    const int lane = tid & 63;
    const int w = tid >> 6;        // 0..3
    const int wm = w >> 1;         // 0..1 row-wave (64 rows each)
    const int wd = w & 1;          // 0..1 col-wave (32 cols each)

    // bijective XCD chunking; mb-major within XCD (12 same-mb blocks adjacent
    // -> H tile served from L2/L3, weights L3-resident)
    const int nwg = mblocks * 12;
    const int orig = blockIdx.x;
    const int xcd = orig & 7, qx = nwg >> 3, rx = nwg & 7;
    const int v = (xcd < rx ? xcd * (qx + 1) : rx * (qx + 1) + (xcd - rx) * qx) + (orig >> 3);
    const int mb = v / 12;
    const int d0c = v - mb * 12;
    const int mBase = mb * 128;
    const int d0 = d0c * 64;

    // ---- stage-source precompute (compile-time A/B slot split: s<4 = A) ----
    const int l3 = lane >> 3, j = lane & 7;
    const int rbase = w * 8 + l3;          // 0..31
    const int jjA = j ^ l3;                // (rA&7) == l3 for all s
    unsigned offH[4];
#pragma unroll
    for (int s = 0; s < 4; ++s) {
        int gr = mBase + s * 32 + rbase;
        if (gr >= M) gr = M - 1;
        offH[s] = (unsigned)(2 * gr + (jjA >> 2)) * ROWB + (jjA & 3) * 16;
    }
    const int pB = w * 8 + l3;             // 0..31
    const int jjB = j ^ (pB & 7);
    const unsigned offWcol = (unsigned)(d0 + 2 * pB + (jjB >> 2)) * ROWB + (jjB & 3) * 16;
    const int wK = w * 1024;               // uniform part of LDS dest

#define STAGE(bi, ko) do { \
    _Pragma("unroll") for (int s = 0; s < 4; ++s) \
        gload16((const char*)Hc + offH[s] + (ko), smem + (bi) * BUFB + s * 4096 + wK); \
    _Pragma("unroll") for (int s = 0; s < 5; ++s) \
        gload16((const char*)Bw + (size_t)s * MATB + offWcol + (ko), \
                smem + (bi) * BUFB + 16384 + s * 4096 + wK); \
} while (0)

    // ---- compute offsets (kt-invariant) ----
    const int q = lane >> 4;       // K-slice / C-row-group
    const int lr = lane & 15;
    int offA[4], offB[2];
#pragma unroll
    for (int fm = 0; fm < 4; ++fm) {
        int r = wm * 64 + fm * 16 + lr;
        offA[fm] = r * 128 + ((q ^ (r & 7)) * 16);
    }
#pragma unroll
    for (int fd = 0; fd < 2; ++fd) {
        int cl = wd * 32 + fd * 16 + lr;
        int p = cl >> 1;
        int jb = ((cl & 1) * 4 + q) ^ (p & 7);
        offB[fd] = 16384 + p * 128 + jb * 16;
    }

    f32x4 acc[5][4][2];
#pragma unroll
    for (int g = 0; g < 5; ++g)
#pragma unroll
        for (int a = 0; a < 4; ++a)
#pragma unroll
            for (int b = 0; b < 2; ++b)
                acc[g][a][b] = (f32x4){0.f, 0.f, 0.f, 0.f};

    // ---- main loop ----
    STAGE(0, 0);
    int cur = 0;
    for (int kt = 0; kt < NT; ++kt) {
        if (kt + 1 < NT) {
            STAGE(cur ^ 1, (kt + 1) * 64);                // full-kt landing window
            asm volatile("s_waitcnt vmcnt(9)" ::: "memory");
        } else {
            asm volatile("s_waitcnt vmcnt(0)" ::: "memory");
        }
        __builtin_amdgcn_s_barrier();                     // B1: buf[cur] landed
        const char* bb = smem + cur * BUFB;

        // ---- phase A: A-frags + B(fd=0), MFMA fd=0 ----
        half8 hl[4], hr[4], hs[4];
        half8 bfrag[5];
#pragma unroll
        for (int fm = 0; fm < 4; ++fm) {
            hl[fm] = *(const half8*)(bb + offA[fm]);
            hr[fm] = *(const half8*)(bb + (offA[fm] ^ 64));
            hs[fm] = hl[fm] + hr[fm];
        }
#pragma unroll
        for (int t = 0; t < 5; ++t)
            bfrag[t] = *(const half8*)(bb + offB[0] + t * 4096);
        __builtin_amdgcn_s_setprio(1);
#pragma unroll
        for (int fm = 0; fm < 4; ++fm) {
            acc[0][fm][0] = __builtin_amdgcn_mfma_f32_16x16x32_f16(hs[fm], bfrag[0], acc[0][fm][0], 0, 0, 0);
            acc[1][fm][0] = __builtin_amdgcn_mfma_f32_16x16x32_f16(hs[fm], bfrag[1], acc[1][fm][0], 0, 0, 0);
            acc[2][fm][0] = __builtin_amdgcn_mfma_f32_16x16x32_f16(hs[fm], bfrag[2], acc[2][fm][0], 0, 0, 0);
            acc[3][fm][0] = __builtin_amdgcn_mfma_f32_16x16x32_f16(hl[fm], bfrag[3], acc[3][fm][0], 0, 0, 0);
            acc[3][fm][0] = __builtin_amdgcn_mfma_f32_16x16x32_f16(hr[fm], bfrag[4], acc[3][fm][0], 0, 0, 0);
            acc[4][fm][0] = __builtin_amdgcn_mfma_f32_16x16x32_f16(hl[fm], bfrag[4], acc[4][fm][0], 0, 0, 0);
            acc[4][fm][0] = __builtin_amdgcn_mfma_f32_16x16x32_f16(hr[fm], bfrag[3], acc[4][fm][0], 0, 0, 0);
        }
        __builtin_amdgcn_s_setprio(0);
        __builtin_amdgcn_sched_barrier(0);
        __builtin_amdgcn_s_barrier();                     // mid-phase boundary (sched only)
        __builtin_amdgcn_sched_barrier(0);

        // ---- phase B: B(fd=1), MFMA fd=1 ----
#pragma unroll
        for (int t = 0; t < 5; ++t)
            bfrag[t] = *(const half8*)(bb + offB[1] + t * 4096);
        __builtin_amdgcn_s_setprio(1);
#pragma unroll
        for (int fm = 0; fm < 4; ++fm) {
            acc[0][fm][1] = __builtin_amdgcn_mfma_f32_16x16x32_f16(hs[fm], bfrag[0], acc[0][fm][1], 0, 0, 0);
            acc[1][fm][1] = __builtin_amdgcn_mfma_f32_16x16x32_f16(hs[fm], bfrag[1], acc[1][fm][1], 0, 0, 0);
            acc[2][fm][1] = __builtin_amdgcn_mfma_f32_16x16x32_f16(hs[fm], bfrag[2], acc[2][fm][1], 0, 0, 0);
            acc[3][fm][1] = __builtin_amdgcn_mfma_f32_16x16x32_f16(hl[fm], bfrag[3], acc[3][fm][1], 0, 0, 0);
            acc[3][fm][1] = __builtin_amdgcn_mfma_f32_16x16x32_f16(hr[fm], bfrag[4], acc[3][fm][1], 0, 0, 0);
            acc[4][fm][1] = __builtin_amdgcn_mfma_f32_16x16x32_f16(hl[fm], bfrag[4], acc[4][fm][1], 0, 0, 0);
            acc[4][fm][1] = __builtin_amdgcn_mfma_f32_16x16x32_f16(hr[fm], bfrag[3], acc[4][fm][1], 0, 0, 0);
        }
        __builtin_amdgcn_s_setprio(0);
        if (kt + 1 < NT) __builtin_amdgcn_s_barrier();    // B2: done reading buf[cur]
        cur ^= 1;
    }

    // ---- LSTM cell epilogue, in-register ----
#pragma unroll
    for (int fd = 0; fd < 2; ++fd) {
        const int col = d0 + wd * 32 + fd * 16 + lr;
        const float bi = biou[col];
        const float bo = biou[768 + col];
        const float bu = biou[1536 + col];
        const float bf = bfv[col];
#pragma unroll
        for (int fm = 0; fm < 4; ++fm) {
            const int rb = mBase + wm * 64 + fm * 16 + q * 4;
#pragma unroll
            for (int r4 = 0; r4 < 4; ++r4) {
                int row = rb + r4;
                if (row < M) {
                    float iv = acc[0][fm][fd][r4] + bi;
                    float ov = acc[1][fm][fd][r4] + bo;
                    float uv = acc[2][fm][fd][r4] + bu;
                    float fl = sigm(acc[3][fm][fd][r4] + bf);
                    float fr = sigm(acc[4][fm][fd][r4] + bf);
                    float clv = 0.f, crv = 0.f;
                    if (!firstLevel) {
                        clv = Cc[(size_t)(2 * row) * 768 + col];
                        crv = Cc[(size_t)(2 * row + 1) * 768 + col];
                    }
                    float c = sigm(iv) * tanhfast(uv) + fl * clv + fr * crv;
                    float h = sigm(ov) * tanhfast(c);
                    if (finalLevel) {
                        outH[row * 768 + col] = h;
                        outC[row * 768 + col] = c;
                    } else {
                        Hn[(size_t)row * 768 + col] = (_Float16)h;
                        Cn[(size_t)row * 768 + col] = c;
                    }
                }
            }
        }
    }
}

extern "C" void kernel_launch(void* const* d_in, const int* in_sizes, int n_in,
                              void* d_out, int out_size, void* d_ws, size_t ws_size,
                              hipStream_t stream)
{
    const float* leaf = (const float*)d_in[0];
    const float* Wiou = (const float*)d_in[1];
    const float* biou = (const float*)d_in[2];
    const float* Uiou = (const float*)d_in[3];
    const float* Wf   = (const float*)d_in[4];
    const float* bfv  = (const float*)d_in[5];
    const float* Uf   = (const float*)d_in[6];

    char* ws = (char*)d_ws;
    _Float16* Bw = (_Float16*)(ws);                  // 5x768x768 fp16 = 5,898,240 B
    _Float16* H0 = (_Float16*)(ws + 5898240);        // 65536x768 fp16
    _Float16* H1 = (_Float16*)(ws + 106561536);      // 32768x768 fp16
    float*    C0 = (float*)(ws + 156893184);         // 32768x768 f32
    float*    C1 = (float*)(ws + 257556480);         // 16384x768 f32

    prep_weights<<<1024, 256, 0, stream>>>(Wiou, Uiou, Wf, Uf, Bw);
    cast_leaves<<<2048, 256, 0, stream>>>(leaf, H0, 50331648 / 8);

    float* out = (float*)d_out;  // [2,8,768]
    _Float16* Hc = H0; _Float16* Hn = H1;
    float* Cc = C1; float* Cn = C0;
    int rows = 65536, level = 0;
    while (rows > 8) {
        int M = rows >> 1;
        int fin = (M == 8) ? 1 : 0;
        int mblocks = (M + 127) / 128;
        tree_level<<<mblocks * 12, 256, 0, stream>>>(Hc, Cc, Bw, biou, bfv,
            Hn, Cn, fin ? out : (float*)nullptr, fin ? out + 6144 : (float*)nullptr,
            M, mblocks, level == 0 ? 1 : 0, fin);
        _Float16* th = Hc; Hc = Hn; Hn = th;
        float* tc = Cc; Cc = Cn; Cn = tc;
        rows = M; ++level;
    }
}

// Round 7
// 982.468 us; speedup vs baseline: 1.2508x; 1.0573x over previous
//
#include <hip/hip_runtime.h>

// Child-Sum Tree-LSTM, level-synchronous, B=8 L=8192 D=768.
// Per level: 5 fused K=768 GEMM products + LSTM cell epilogue.
//   acc0..2 (i,o,u) = hs @ (0.5*W_iou + U_iou)^T
//   acc3 (fl-pre)   = hl@Wfp^T + hr@Wfh^T,  Wfp = 0.5*W_f + U_f, Wfh = 0.5*W_f
//   acc4 (fr-pre)   = hl@Wfh^T + hr@Wfp^T
// fp16 MFMA 16x16x32, fp32 accum. Block = 128 rows x 32 cols, 256 thr
// (4 waves 2x2, wave tile 64x16, fd=1 -> acc 80 AGPR). Double-buffered 26KB
// LDS -> THREE blocks/CU (159.7/160 KB): cross-block TLP breaks the
// 2-barrier lockstep (m114/m97 mechanism). global_load_lds staging (7/wave,
// counted vmcnt(7)), source-side XOR swizzle, mb-major XCD block order.

typedef _Float16 half8 __attribute__((ext_vector_type(8)));
typedef float f32x4 __attribute__((ext_vector_type(4)));

#define ROWB 1536        // bytes per 768-elem fp16 row
#define NT 24            // 768 / 32
#define BUFB 26624       // A 16384 + B 10240
#define BOFF 16384

__device__ __forceinline__ float sigm(float x){ return 1.f/(1.f+__expf(-x)); }
__device__ __forceinline__ float tanhfast(float x){ return 1.f - 2.f/(1.f+__expf(2.f*x)); }

__device__ __forceinline__ void gload16(const void* g, void* l){
  __builtin_amdgcn_global_load_lds((const __attribute__((address_space(1))) void*)g,
                                   (__attribute__((address_space(3))) void*)l, 16, 0, 0);
}

// Bw: 5 mats of 768x768 fp16: [0..2]=0.5*W_iou+U_iou (i,o,u), [3]=0.5*Wf+Uf, [4]=0.5*Wf
__global__ void prep_weights(const float* __restrict__ Wiou, const float* __restrict__ Uiou,
                             const float* __restrict__ Wf, const float* __restrict__ Uf,
                             _Float16* __restrict__ Bw)
{
    const int n1 = 2304 * 768, n2 = n1 + 589824, n3 = n2 + 589824;
    int stride = gridDim.x * blockDim.x;
    for (int idx = blockIdx.x * blockDim.x + threadIdx.x; idx < n3; idx += stride) {
        float v;
        if (idx < n1)      v = __fmaf_rn(0.5f, Wiou[idx], Uiou[idx]);
        else if (idx < n2) { int k = idx - n1; v = __fmaf_rn(0.5f, Wf[k], Uf[k]); }
        else               { int k = idx - n2; v = 0.5f * Wf[k]; }
        Bw[idx] = (_Float16)v;
    }
}

__global__ void cast_leaves(const float* __restrict__ x, _Float16* __restrict__ h, int n8)
{
    int stride = gridDim.x * blockDim.x;
    for (int i = blockIdx.x * blockDim.x + threadIdx.x; i < n8; i += stride) {
        float4 v0 = ((const float4*)x)[2 * i];
        float4 v1 = ((const float4*)x)[2 * i + 1];
        half8 o = { (_Float16)v0.x, (_Float16)v0.y, (_Float16)v0.z, (_Float16)v0.w,
                    (_Float16)v1.x, (_Float16)v1.y, (_Float16)v1.z, (_Float16)v1.w };
        ((half8*)h)[i] = o;
    }
}

// LDS per buffer:
//  A: 128 rows x 128B. Row r chunk j: jj=j^(r&7); side=jj>>2 (0=HL,1=HR),
//     kchunk=jj&3 of H row 2*(mBase+r)+side.
//  B at +16384: 5 mats x 16 pairs x 128B (mat stride 2048). Pair p chunk j:
//     jj=j^(p&7); col=d0+2p+(jj>>2), kchunk=jj&3.
__global__ __launch_bounds__(256, 3) void tree_level(
    const _Float16* __restrict__ Hc, const float* __restrict__ Cc,
    const _Float16* __restrict__ Bw,
    const float* __restrict__ biou, const float* __restrict__ bfv,
    _Float16* __restrict__ Hn, float* __restrict__ Cn,
    float* __restrict__ outH, float* __restrict__ outC,
    int M, int mblocks, int firstLevel, int finalLevel)
{
    __shared__ __align__(16) char smem[2 * BUFB];
    const int tid = threadIdx.x;
    const int lane = tid & 63;
    const int w = tid >> 6;        // 0..3
    const int wm = w >> 1;         // 0..1 row-wave (64 rows each)
    const int wd = w & 1;          // 0..1 col-wave (16 cols each)

    // bijective XCD chunking; mb-major within XCD (24 same-mb blocks adjacent
    // -> H tile served from L2/L3, weights L2/L3-resident)
    const int nwg = mblocks * 24;
    const int orig = blockIdx.x;
    const int xcd = orig & 7, qx = nwg >> 3, rx = nwg & 7;
    const int v = (xcd < rx ? xcd * (qx + 1) : rx * (qx + 1) + (xcd - rx) * qx) + (orig >> 3);
    const int mb = v / 24;
    const int d0c = v - mb * 24;
    const int mBase = mb * 128;
    const int d0 = d0c * 32;

    // ---- stage-source precompute: 28 uniform slots, 7 per wave ----
    // A: slots s=0..3, instr u = s*4+w covers rows u*8 + l3
    // B: slots s=4..6, instr i = (s-4)*4+w (i>=10 duplicates i-2, benign)
    const int l3 = lane >> 3, j = lane & 7;
    const int jj0 = j ^ l3;        // (row&7)==l3 for both A rows and B pairs
    unsigned offHa[4], offWb[3];
    int dstA[4], dstB[3];
#pragma unroll
    for (int s = 0; s < 4; ++s) {
        int u = s * 4 + w;
        int gr = mBase + u * 8 + l3;
        if (gr >= M) gr = M - 1;
        offHa[s] = (unsigned)(2 * gr + (jj0 >> 2)) * ROWB + (jj0 & 3) * 16;
        dstA[s] = u * 1024;
    }
#pragma unroll
    for (int s = 0; s < 3; ++s) {
        int i = s * 4 + w;
        if (i >= 10) i -= 2;
        int t = i >> 1, half = i & 1;
        int p = half * 8 + l3;
        int cl = 2 * p + (jj0 >> 2);
        offWb[s] = (unsigned)(t * 768 + d0 + cl) * ROWB + (jj0 & 3) * 16;
        dstB[s] = BOFF + t * 2048 + half * 1024;
    }

#define STAGE(bi, ko) do { \
    _Pragma("unroll") for (int s = 0; s < 4; ++s) \
        gload16((const char*)Hc + offHa[s] + (ko), smem + (bi) * BUFB + dstA[s]); \
    _Pragma("unroll") for (int s = 0; s < 3; ++s) \
        gload16((const char*)Bw + offWb[s] + (ko), smem + (bi) * BUFB + dstB[s]); \
} while (0)

    // ---- compute offsets (kt-invariant) ----
    const int q = lane >> 4;       // K-slice / C-row-group
    const int lr = lane & 15;
    int offA[4];
#pragma unroll
    for (int fm = 0; fm < 4; ++fm) {
        int r = wm * 64 + fm * 16 + lr;
        offA[fm] = r * 128 + ((q ^ (r & 7)) * 16);
    }
    int offB;
    {
        int cl = wd * 16 + lr;
        int p = cl >> 1;
        int jb = ((cl & 1) * 4 + q) ^ (p & 7);
        offB = BOFF + p * 128 + jb * 16;
    }

    f32x4 acc[5][4];
#pragma unroll
    for (int g = 0; g < 5; ++g)
#pragma unroll
        for (int a = 0; a < 4; ++a)
            acc[g][a] = (f32x4){0.f, 0.f, 0.f, 0.f};

    // ---- main loop: 2-deep, counted vmcnt(7), raw barrier pair ----
    STAGE(0, 0);
    int cur = 0;
    for (int kt = 0; kt < NT; ++kt) {
        if (kt + 1 < NT) {
            STAGE(cur ^ 1, (kt + 1) * 64);                // full-kt landing window
            asm volatile("s_waitcnt vmcnt(7)" ::: "memory");
        } else {
            asm volatile("s_waitcnt vmcnt(0)" ::: "memory");
        }
        __builtin_amdgcn_s_barrier();                     // buf[cur] landed for all waves
        __builtin_amdgcn_sched_barrier(0);
        const char* bb = smem + cur * BUFB;
        half8 b0 = *(const half8*)(bb + offB);
        half8 b1 = *(const half8*)(bb + offB + 2048);
        half8 b2 = *(const half8*)(bb + offB + 4096);
        half8 b3 = *(const half8*)(bb + offB + 6144);     // Wfp
        half8 b4 = *(const half8*)(bb + offB + 8192);     // Wfh
        __builtin_amdgcn_s_setprio(1);
#pragma unroll
        for (int fm = 0; fm < 4; ++fm) {
            half8 hl = *(const half8*)(bb + offA[fm]);
            half8 hr = *(const half8*)(bb + (offA[fm] ^ 64));
            acc[3][fm] = __builtin_amdgcn_mfma_f32_16x16x32_f16(hl, b3, acc[3][fm], 0, 0, 0);
            acc[4][fm] = __builtin_amdgcn_mfma_f32_16x16x32_f16(hl, b4, acc[4][fm], 0, 0, 0);
            half8 hs = hl + hr;
            acc[0][fm] = __builtin_amdgcn_mfma_f32_16x16x32_f16(hs, b0, acc[0][fm], 0, 0, 0);
            acc[1][fm] = __builtin_amdgcn_mfma_f32_16x16x32_f16(hs, b1, acc[1][fm], 0, 0, 0);
            acc[2][fm] = __builtin_amdgcn_mfma_f32_16x16x32_f16(hs, b2, acc[2][fm], 0, 0, 0);
            acc[3][fm] = __builtin_amdgcn_mfma_f32_16x16x32_f16(hr, b4, acc[3][fm], 0, 0, 0);
            acc[4][fm] = __builtin_amdgcn_mfma_f32_16x16x32_f16(hr, b3, acc[4][fm], 0, 0, 0);
        }
        __builtin_amdgcn_s_setprio(0);
        if (kt + 1 < NT) __builtin_amdgcn_s_barrier();    // all waves done reading buf[cur]
        cur ^= 1;
    }

    // ---- LSTM cell epilogue, in-register ----
    const int col = d0 + wd * 16 + lr;
    const float bi = biou[col];
    const float bo = biou[768 + col];
    const float bu = biou[1536 + col];
    const float bf = bfv[col];
#pragma unroll
    for (int fm = 0; fm < 4; ++fm) {
        const int rb = mBase + wm * 64 + fm * 16 + q * 4;
#pragma unroll
        for (int r4 = 0; r4 < 4; ++r4) {
            int row = rb + r4;
            if (row < M) {
                float iv = acc[0][fm][r4] + bi;
                float ov = acc[1][fm][r4] + bo;
                float uv = acc[2][fm][r4] + bu;
                float fl = sigm(acc[3][fm][r4] + bf);
                float fr = sigm(acc[4][fm][r4] + bf);
                float clv = 0.f, crv = 0.f;
                if (!firstLevel) {
                    clv = Cc[(size_t)(2 * row) * 768 + col];
                    crv = Cc[(size_t)(2 * row + 1) * 768 + col];
                }
                float c = sigm(iv) * tanhfast(uv) + fl * clv + fr * crv;
                float h = sigm(ov) * tanhfast(c);
                if (finalLevel) {
                    outH[row * 768 + col] = h;
                    outC[row * 768 + col] = c;
                } else {
                    Hn[(size_t)row * 768 + col] = (_Float16)h;
                    Cn[(size_t)row * 768 + col] = c;
                }
            }
        }
    }
}

extern "C" void kernel_launch(void* const* d_in, const int* in_sizes, int n_in,
                              void* d_out, int out_size, void* d_ws, size_t ws_size,
                              hipStream_t stream)
{
    const float* leaf = (const float*)d_in[0];
    const float* Wiou = (const float*)d_in[1];
    const float* biou = (const float*)d_in[2];
    const float* Uiou = (const float*)d_in[3];
    const float* Wf   = (const float*)d_in[4];
    const float* bfv  = (const float*)d_in[5];
    const float* Uf   = (const float*)d_in[6];

    char* ws = (char*)d_ws;
    _Float16* Bw = (_Float16*)(ws);                  // 5x768x768 fp16 = 5,898,240 B
    _Float16* H0 = (_Float16*)(ws + 5898240);        // 65536x768 fp16
    _Float16* H1 = (_Float16*)(ws + 106561536);      // 32768x768 fp16
    float*    C0 = (float*)(ws + 156893184);         // 32768x768 f32
    float*    C1 = (float*)(ws + 257556480);         // 16384x768 f32

    prep_weights<<<1024, 256, 0, stream>>>(Wiou, Uiou, Wf, Uf, Bw);
    cast_leaves<<<2048, 256, 0, stream>>>(leaf, H0, 50331648 / 8);

    float* out = (float*)d_out;  // [2,8,768]
    _Float16* Hc = H0; _Float16* Hn = H1;
    float* Cc = C1; float* Cn = C0;
    int rows = 65536, level = 0;
    while (rows > 8) {
        int M = rows >> 1;
        int fin = (M == 8) ? 1 : 0;
        int mblocks = (M + 127) / 128;
        tree_level<<<mblocks * 24, 256, 0, stream>>>(Hc, Cc, Bw, biou, bfv,
            Hn, Cn, fin ? out : (float*)nullptr, fin ? out + 6144 : (float*)nullptr,
            M, mblocks, level == 0 ? 1 : 0, fin);
        _Float16* th = Hc; Hc = Hn; Hn = th;
        float* tc = Cc; Cc = Cn; Cn = tc;
        rows = M; ++level;
    }
}